// Round 1
// baseline (64.666 us; speedup 1.0000x reference)
//
#include <hip/hip_runtime.h>
#include <math.h>

#define BB 128   // batch
#define VV 4     // views
#define NN 512   // BB*VV rows
#define DD 128   // feature dim
#define NT 512   // threads per block (8 waves) -- was 256; TLP + serial-depth fix
#define RT 256   // reduce kernel threads

// ---------------------------------------------------------------------------
// One block per anchor, now 8 waves/block. Single fused read pass over all
// 512 rows computes BOTH ss_j = <row_j, row_j> and dot_j = <row_j, anchor>
// (8 lanes per row, 4 float4 loads/lane, 3-step butterfly reduce). Each wave
// covers 64 rows in 8 iterations (was 128 rows / 16 iters at NT=256): half
// the per-block serial critical path, 2x the waves/SIMD for latency hiding.
// Distance + ballot compaction are now a single round (NT == NN).
// Math is bit-identical to the round-2-verified version (absmax 0.0):
//   d_j = sqrt(max(sn_a + sn_j - 2*dot_j*inv_a*inv_j, 0))
// Writes deterministic per-anchor partials (no init, no global atomics).
// ---------------------------------------------------------------------------
__global__ __launch_bounds__(NT)
void fused_triplet(const float* __restrict__ feat,
                   const int* __restrict__ labels,
                   float* __restrict__ psum,
                   float* __restrict__ pcnt) {
    __shared__ float s_ss[NN];
    __shared__ float s_dot[NN];
    __shared__ float s_pos[NN];
    __shared__ float s_neg[NN];
    __shared__ int   s_lab[BB];
    __shared__ int   s_np, s_nn;
    __shared__ float s_wsum[NT / 64];
    __shared__ unsigned int s_wcnt[NT / 64];

    const int a    = blockIdx.x;
    const int tid  = threadIdx.x;
    const int wave = tid >> 6;      // 0..7
    const int lane = tid & 63;
    const int grp  = lane >> 3;     // 8 row-groups of 8 lanes
    const int l8   = lane & 7;

    if (tid < BB) s_lab[tid] = labels[tid];
    if (tid == 0) { s_np = 0; s_nn = 0; }

    // anchor row fragments: this lane's 4 float4s (positions l8, l8+8, ...)
    const int ab = a & (BB - 1), av = a >> 7;
    const float4* arow = (const float4*)(feat + (size_t)ab * (VV * DD) + av * DD);
    float4 af0 = arow[l8];
    float4 af1 = arow[l8 + 8];
    float4 af2 = arow[l8 + 16];
    float4 af3 = arow[l8 + 24];

    // fused ss + dot pass: wave w covers rows [w*64, w*64+64), 8 rows/iter
    #pragma unroll 4
    for (int it = 0; it < 8; ++it) {
        const int j  = (wave << 6) + (it << 3) + grp;
        const int jb = j & (BB - 1), jv = j >> 7;
        const float4* jrow = (const float4*)(feat + (size_t)jb * (VV * DD) + jv * DD);
        float4 x0 = jrow[l8];
        float4 x1 = jrow[l8 + 8];
        float4 x2 = jrow[l8 + 16];
        float4 x3 = jrow[l8 + 24];

        float ss = 0.f, dt = 0.f;
        ss = fmaf(x0.x, x0.x, fmaf(x0.y, x0.y, fmaf(x0.z, x0.z, fmaf(x0.w, x0.w, ss))));
        ss = fmaf(x1.x, x1.x, fmaf(x1.y, x1.y, fmaf(x1.z, x1.z, fmaf(x1.w, x1.w, ss))));
        ss = fmaf(x2.x, x2.x, fmaf(x2.y, x2.y, fmaf(x2.z, x2.z, fmaf(x2.w, x2.w, ss))));
        ss = fmaf(x3.x, x3.x, fmaf(x3.y, x3.y, fmaf(x3.z, x3.z, fmaf(x3.w, x3.w, ss))));
        dt = fmaf(x0.x, af0.x, fmaf(x0.y, af0.y, fmaf(x0.z, af0.z, fmaf(x0.w, af0.w, dt))));
        dt = fmaf(x1.x, af1.x, fmaf(x1.y, af1.y, fmaf(x1.z, af1.z, fmaf(x1.w, af1.w, dt))));
        dt = fmaf(x2.x, af2.x, fmaf(x2.y, af2.y, fmaf(x2.z, af2.z, fmaf(x2.w, af2.w, dt))));
        dt = fmaf(x3.x, af3.x, fmaf(x3.y, af3.y, fmaf(x3.z, af3.z, fmaf(x3.w, af3.w, dt))));

        // butterfly reduce across the 8 lanes of this row group
        #pragma unroll
        for (int off = 4; off > 0; off >>= 1) {
            ss += __shfl_xor(ss, off);
            dt += __shfl_xor(dt, off);
        }
        if (l8 == 0) { s_ss[j] = ss; s_dot[j] = dt; }
    }
    __syncthreads();

    // distance for j = tid (single round: NT == NN)
    const float ssa  = s_ss[a];
    const float inva = 1.f / fmaxf(sqrtf(ssa), 1e-12f);
    const float sna  = ssa * inva * inva;
    const int   j    = tid;
    const float ssj  = s_ss[j];
    const float invj = 1.f / fmaxf(sqrtf(ssj), 1e-12f);
    const float snj  = ssj * invj * invj;
    const float dot  = s_dot[j] * inva * invj;
    const float sq   = fmaxf(sna + snj - 2.f * dot, 0.f);
    const float d    = (sq > 0.f) ? sqrtf(sq) : 0.f;   // safe_sqrt semantics

    // ballot compaction into pos/neg lists (2 LDS atomics per wave)
    const int la   = s_lab[ab];
    const bool same  = (s_lab[j & (BB - 1)] == la);
    const bool ispos = same & (j != a);
    const bool isneg = !same;
    unsigned long long mp = __ballot(ispos);
    unsigned long long mn = __ballot(isneg);
    int basep = 0, basen = 0;
    if (lane == 0) {
        basep = atomicAdd(&s_np, (int)__popcll(mp));
        basen = atomicAdd(&s_nn, (int)__popcll(mn));
    }
    basep = __shfl(basep, 0);
    basen = __shfl(basen, 0);
    unsigned long long below = (1ull << lane) - 1ull;
    if (ispos) s_pos[basep + (int)__popcll(mp & below)] = d;
    if (isneg) s_neg[basen + (int)__popcll(mn & below)] = d;
    __syncthreads();

    // pair loop: each thread owns ONE negative (register), positives broadcast
    const int np = s_np, nn = s_nn;
    const bool  vn = tid < nn;
    const float dn = s_neg[vn ? tid : 0];
    float lsum = 0.f;
    unsigned int lcnt = 0;
    for (int p = 0; p < np; ++p) {
        float diff = s_pos[p] - dn;          // s_pos[p] is an LDS broadcast
        if (vn & (diff > 0.f)) { lsum += diff; lcnt++; }
    }

    #pragma unroll
    for (int off = 32; off > 0; off >>= 1) {
        lsum += __shfl_down(lsum, off);
        lcnt += __shfl_down(lcnt, off);
    }
    if (lane == 0) { s_wsum[wave] = lsum; s_wcnt[wave] = lcnt; }
    __syncthreads();
    if (tid == 0) {
        float S = 0.f;
        unsigned int C = 0;
        #pragma unroll
        for (int w = 0; w < NT / 64; ++w) { S += s_wsum[w]; C += s_wcnt[w]; }
        psum[a] = S;
        pcnt[a] = (float)C;
    }
}

// ---------------------------------------------------------------------------
// Final reduce: 512 partials -> scalar
// ---------------------------------------------------------------------------
__global__ __launch_bounds__(RT)
void reduce_final(const float* __restrict__ psum,
                  const float* __restrict__ pcnt,
                  float* __restrict__ out) {
    int tid = threadIdx.x;
    float s = psum[tid] + psum[tid + RT];
    float c = pcnt[tid] + pcnt[tid + RT];
    #pragma unroll
    for (int off = 32; off > 0; off >>= 1) {
        s += __shfl_down(s, off);
        c += __shfl_down(c, off);
    }
    __shared__ float ws[RT / 64], wc[RT / 64];
    if ((tid & 63) == 0) { ws[tid >> 6] = s; wc[tid >> 6] = c; }
    __syncthreads();
    if (tid == 0) {
        float S = ws[0] + ws[1] + ws[2] + ws[3];
        float C = wc[0] + wc[1] + wc[2] + wc[3];
        out[0] = (C > 0.f) ? S / C : 0.f;
    }
}

extern "C" void kernel_launch(void* const* d_in, const int* in_sizes, int n_in,
                              void* d_out, int out_size, void* d_ws, size_t ws_size,
                              hipStream_t stream) {
    const float* feat   = (const float*)d_in[0];   // [128, 4, 128] fp32
    const int*   labels = (const int*)d_in[1];     // [128] int32
    float* out = (float*)d_out;

    float* psum = (float*)d_ws;          // NN floats
    float* pcnt = psum + NN;             // NN floats

    fused_triplet<<<NN, NT, 0, stream>>>(feat, labels, psum, pcnt);
    reduce_final<<<1, RT, 0, stream>>>(psum, pcnt, out);
}